// Round 1
// baseline (373.639 us; speedup 1.0000x reference)
//
#include <hip/hip_runtime.h>
#include <stdint.h>

#define DEV __device__ __forceinline__

typedef __attribute__((ext_vector_type(8))) short bf16x8;
typedef __attribute__((ext_vector_type(4))) float f32x4;
typedef __attribute__((ext_vector_type(8))) unsigned short u16x8;
typedef __attribute__((ext_vector_type(4))) unsigned short u16x4;

DEV unsigned short f2bf(float f) {
  union { float f; unsigned int u; } v; v.f = f;
  unsigned int u = v.u;
  return (unsigned short)((u + 0x7FFFu + ((u >> 16) & 1u)) >> 16);
}

DEV f32x4 mfma16(bf16x8 a, bf16x8 b, f32x4 c) {
  return __builtin_amdgcn_mfma_f32_16x16x32_bf16(a, b, c, 0, 0, 0);
}

DEV void gl_lds16(const void* g, void* l) {
  __builtin_amdgcn_global_load_lds(
      (const __attribute__((address_space(1))) void*)g,
      (__attribute__((address_space(3))) void*)l, 16, 0, 0);
}

// ---------------- convert x (fp32 -> bf16), vectorized ----------------
__global__ __launch_bounds__(256) void k_cvt_bf16(const float* __restrict__ in,
                                                  unsigned short* __restrict__ out,
                                                  int n8) {
  int i = blockIdx.x * 256 + threadIdx.x;
  if (i >= n8) return;
  const float4* p = (const float4*)in + (size_t)i * 2;
  float4 a = p[0], b = p[1];
  u16x8 o;
  o[0] = f2bf(a.x); o[1] = f2bf(a.y); o[2] = f2bf(a.z); o[3] = f2bf(a.w);
  o[4] = f2bf(b.x); o[5] = f2bf(b.y); o[6] = f2bf(b.z); o[7] = f2bf(b.w);
  ((u16x8*)out)[i] = o;
}

// -------- fused weights: WkvT[o][c] = sum_d Wx[c][hb+d] * W{k,v}[d][dp] --------
__global__ __launch_bounds__(256) void k_fuse_wkv(const float* __restrict__ Wx,
                                                  const float* __restrict__ Wk,
                                                  const float* __restrict__ Wv,
                                                  unsigned short* __restrict__ WkvT) {
  int idx = blockIdx.x * 256 + threadIdx.x;  // 524288
  int o = idx >> 9;                          // 0..1023
  int c = idx & 511;
  const float* W = (o < 512) ? Wk : Wv;
  int oo = o & 511;
  int hb = oo & ~63;  // h*64
  int dp = oo & 63;
  float s = 0.f;
#pragma unroll 8
  for (int d = 0; d < 64; ++d) s += Wx[(size_t)c * 512 + hb + d] * W[d * 64 + dp];
  WkvT[(size_t)o * 512 + c] = f2bf(s);
}

__global__ void k_fuse_bias(const float* __restrict__ bx, const float* __restrict__ bk,
                            const float* __restrict__ bv, const float* __restrict__ Wk,
                            const float* __restrict__ Wv, float* __restrict__ bkv) {
  int o = blockIdx.x * 256 + threadIdx.x;  // 1024
  if (o >= 1024) return;
  const float* W = (o < 512) ? Wk : Wv;
  const float* bb = (o < 512) ? bk : bv;
  int oo = o & 511, hb = oo & ~63, dp = oo & 63;
  float s = bb[dp];
  for (int d = 0; d < 64; ++d) s += bx[hb + d] * W[d * 64 + dp];
  bkv[o] = s;
}

__global__ void k_wo_t(const float* __restrict__ Wo, unsigned short* __restrict__ WoT) {
  int idx = blockIdx.x * 256 + threadIdx.x;  // 262144
  int i = idx >> 9, o = idx & 511;
  WoT[(size_t)o * 512 + i] = f2bf(Wo[(size_t)i * 512 + o]);
}

// ---------------- GEMM: C[M,Nw] = A[M,512] @ BT[Nw,512]^T + bias ----------------
// m97 structure: 128x128 tile, BK=64, 4 waves (2x2), global_load_lds width 16.
template <int OUT_BF16>
__global__ __launch_bounds__(256) void k_gemm(const unsigned short* __restrict__ A, int lda,
                                              const unsigned short* __restrict__ BT,
                                              const float* __restrict__ bias,
                                              void* __restrict__ Cptr, int ldc) {
  __shared__ unsigned short As[128 * 64];
  __shared__ unsigned short Bs[128 * 64];
  const int tid = threadIdx.x;
  const int w = tid >> 6, lane = tid & 63;
  const int l = lane & 15, g = lane >> 4;
  const int bm = blockIdx.x * 128, bn = blockIdx.y * 128;
  const int wm = (w >> 1) * 64, wn = (w & 1) * 64;
  const int lr = lane >> 3;        // row within 8-row chunk
  const int lc = (lane & 7) * 8;   // k elem offset (16B)
  f32x4 acc[4][4] = {};
  for (int k0 = 0; k0 < 512; k0 += 64) {
#pragma unroll
    for (int i = 0; i < 4; ++i) {
      int q = w * 4 + i;       // 16 chunks of 1KiB
      int row = q * 8 + lr;
      gl_lds16(A + (size_t)(bm + row) * lda + k0 + lc, &As[q * 512]);
      gl_lds16(BT + (size_t)(bn + row) * 512 + k0 + lc, &Bs[q * 512]);
    }
    __syncthreads();
#pragma unroll
    for (int ks = 0; ks < 2; ++ks) {
      bf16x8 af[4], bfr[4];
#pragma unroll
      for (int fm = 0; fm < 4; ++fm)
        af[fm] = *(const bf16x8*)&As[(wm + fm * 16 + l) * 64 + ks * 32 + g * 8];
#pragma unroll
      for (int fn = 0; fn < 4; ++fn)
        bfr[fn] = *(const bf16x8*)&Bs[(wn + fn * 16 + l) * 64 + ks * 32 + g * 8];
#pragma unroll
      for (int fm = 0; fm < 4; ++fm)
#pragma unroll
        for (int fn = 0; fn < 4; ++fn)
          acc[fm][fn] = mfma16(af[fm], bfr[fn], acc[fm][fn]);
    }
    __syncthreads();
  }
#pragma unroll
  for (int fm = 0; fm < 4; ++fm)
#pragma unroll
    for (int fn = 0; fn < 4; ++fn) {
      int col = bn + wn + fn * 16 + l;
      float bcol = bias[col];
#pragma unroll
      for (int r = 0; r < 4; ++r) {
        int row = bm + wm + fm * 16 + g * 4 + r;
        float vv = acc[fm][fn][r] + bcol;
        if (OUT_BF16)
          ((unsigned short*)Cptr)[(size_t)row * ldc + col] = f2bf(vv);
        else
          ((float*)Cptr)[(size_t)row * ldc + col] = vv;
      }
    }
}

// ---------------- transpose v: kv[:,512+h*64+d] -> vT[bh][d][n] ----------------
__global__ __launch_bounds__(256) void k_vT(const unsigned short* __restrict__ kv,
                                            unsigned short* __restrict__ vT) {
  __shared__ unsigned short T[64][72];
  int bh = blockIdx.y, b = bh >> 3, h = bh & 7;
  int n0 = blockIdx.x * 64;
  int tid = threadIdx.x;
#pragma unroll
  for (int j = 0; j < 2; ++j) {
    int cc = j * 256 + tid;  // 0..511
    int nl = cc >> 3, dc = (cc & 7) * 8;
    u16x8 vl = *(const u16x8*)&kv[((size_t)(b * 16384 + n0 + nl)) * 1024 + 512 + h * 64 + dc];
#pragma unroll
    for (int e = 0; e < 8; ++e) T[dc + e][nl] = vl[e];
  }
  __syncthreads();
#pragma unroll
  for (int j = 0; j < 2; ++j) {
    int cc = j * 256 + tid;
    int d = cc >> 3, nc = (cc & 7) * 8;
    u16x8 ov = *(const u16x8*)&T[d][nc];
    *(u16x8*)&vT[((size_t)(bh * 64 + d)) * 16384 + n0 + nc] = ov;
  }
}

// ---------------- pass 1: flash attn, 64 queries x 16384 keys, key-split ----------------
__global__ __launch_bounds__(256) void k_pass1(const unsigned short* __restrict__ kv,
                                               const unsigned short* __restrict__ vT,
                                               const float* __restrict__ qg,
                                               float* __restrict__ zpart,
                                               float* __restrict__ mpart,
                                               float* __restrict__ dpart) {
  __shared__ unsigned short Gs[64 * 72];   // [s][d] pad
  __shared__ unsigned short Ks[128 * 72];  // [n][d] pad
  __shared__ unsigned short Vs[64 * 136];  // [d][n] pad
  __shared__ unsigned short Ps[64 * 136];  // [s][n] pad
  int chunk = blockIdx.x, bh = blockIdx.y;
  int b = bh >> 3, h = bh & 7;
  int tid = threadIdx.x, w = tid >> 6, lane = tid & 63, l = lane & 15, g = lane >> 4;
  {
    int s = tid >> 2, dc = (tid & 3) * 16;
    const float* src = qg + ((size_t)h * 64 + s) * 64 + dc;
    u16x8 o0, o1;
#pragma unroll
    for (int e = 0; e < 8; ++e) { o0[e] = f2bf(src[e]); o1[e] = f2bf(src[8 + e]); }
    *(u16x8*)&Gs[s * 72 + dc] = o0;
    *(u16x8*)&Gs[s * 72 + dc + 8] = o1;
  }
  f32x4 zacc[4] = {};
  float m_run = -1e30f, d_run = 0.f;
  int n_base = chunk * 1024;
  for (int t = 0; t < 8; ++t) {
    int n0 = n_base + t * 128;
#pragma unroll
    for (int i = 0; i < 4; ++i) {  // stage K tile [128][64]
      int cc = i * 256 + tid;
      int nl = cc >> 3, dc = (cc & 7) * 8;
      *(u16x8*)&Ks[nl * 72 + dc] =
          *(const u16x8*)&kv[((size_t)(b * 16384 + n0 + nl)) * 1024 + h * 64 + dc];
    }
#pragma unroll
    for (int i = 0; i < 4; ++i) {  // stage V^T tile [64][128]
      int cc = i * 256 + tid;
      int d = cc >> 4, nc = (cc & 15) * 8;
      *(u16x8*)&Vs[d * 136 + nc] =
          *(const u16x8*)&vT[((size_t)(bh * 64 + d)) * 16384 + n0 + nc];
    }
    __syncthreads();
    // logits^T = K_tile @ G^T : [128 keys, 16 queries per wave]
    f32x4 sacc[8] = {};
#pragma unroll
    for (int ks = 0; ks < 2; ++ks) {
      bf16x8 bq = *(const bf16x8*)&Gs[(w * 16 + l) * 72 + ks * 32 + g * 8];
#pragma unroll
      for (int fm = 0; fm < 8; ++fm) {
        bf16x8 ak = *(const bf16x8*)&Ks[(fm * 16 + l) * 72 + ks * 32 + g * 8];
        sacc[fm] = mfma16(ak, bq, sacc[fm]);
      }
    }
    // online softmax over keys (rows): reduce across g-groups (lanes ^16, ^32)
    float tmax = -1e30f;
#pragma unroll
    for (int fm = 0; fm < 8; ++fm)
#pragma unroll
      for (int r = 0; r < 4; ++r) tmax = fmaxf(tmax, sacc[fm][r]);
    tmax = fmaxf(tmax, __shfl_xor(tmax, 16));
    tmax = fmaxf(tmax, __shfl_xor(tmax, 32));
    float newm = fmaxf(m_run, tmax);
    float scale = __expf(m_run - newm);
    float psum = 0.f;
#pragma unroll
    for (int fm = 0; fm < 8; ++fm) {
      u16x4 pp;
#pragma unroll
      for (int r = 0; r < 4; ++r) {
        float p = __expf(sacc[fm][r] - newm);
        psum += p;
        pp[r] = f2bf(p);
      }
      *(u16x4*)&Ps[(w * 16 + l) * 136 + fm * 16 + g * 4] = pp;
    }
    psum += __shfl_xor(psum, 16);
    psum += __shfl_xor(psum, 32);
    d_run = d_run * scale + psum;
    m_run = newm;
    float sc[4];
#pragma unroll
    for (int r = 0; r < 4; ++r) sc[r] = __shfl(scale, g * 4 + r);
#pragma unroll
    for (int fd = 0; fd < 4; ++fd)
#pragma unroll
      for (int r = 0; r < 4; ++r) zacc[fd][r] *= sc[r];
    // z += P @ v  (A = P rows from Ps, B = v via Vs[d][n])
#pragma unroll
    for (int kc = 0; kc < 4; ++kc) {
      bf16x8 ap = *(const bf16x8*)&Ps[(w * 16 + l) * 136 + kc * 32 + g * 8];
#pragma unroll
      for (int fd = 0; fd < 4; ++fd) {
        bf16x8 bv = *(const bf16x8*)&Vs[(fd * 16 + l) * 136 + kc * 32 + g * 8];
        zacc[fd] = mfma16(ap, bv, zacc[fd]);
      }
    }
    __syncthreads();
  }
  size_t base = ((size_t)bh * 16 + chunk) * 64;
#pragma unroll
  for (int fd = 0; fd < 4; ++fd)
#pragma unroll
    for (int r = 0; r < 4; ++r) {
      int s = w * 16 + g * 4 + r, d = fd * 16 + l;
      zpart[(base + s) * 64 + d] = zacc[fd][r];
    }
  if (g == 0) {
    mpart[base + w * 16 + l] = m_run;
    dpart[base + w * 16 + l] = d_run;
  }
}

// ---------------- reduce partials -> zT bf16 [bh][d][s] ----------------
__global__ void k_zred(const float* __restrict__ zpart, const float* __restrict__ mpart,
                       const float* __restrict__ dpart, unsigned short* __restrict__ zT) {
  int bh = blockIdx.x, tid = threadIdx.x;
  for (int i = 0; i < 16; ++i) {
    int idx = i * 256 + tid;  // 0..4095
    int s = idx >> 6, d = idx & 63;
    float mg = -1e30f;
    for (int c = 0; c < 16; ++c) mg = fmaxf(mg, mpart[((size_t)bh * 16 + c) * 64 + s]);
    float den = 0.f, num = 0.f;
    for (int c = 0; c < 16; ++c) {
      float e = __expf(mpart[((size_t)bh * 16 + c) * 64 + s] - mg);
      den += e * dpart[((size_t)bh * 16 + c) * 64 + s];
      num += e * zpart[(((size_t)bh * 16 + c) * 64 + s) * 64 + d];
    }
    zT[((size_t)bh * 64 + d) * 64 + s] = f2bf(num / den);
  }
}

// ---------------- pass 2: per-token softmax over 64 slots, y = P2 @ z ----------------
__global__ __launch_bounds__(256) void k_pass2(const unsigned short* __restrict__ kv,
                                               const unsigned short* __restrict__ zT,
                                               const float* __restrict__ qg,
                                               unsigned short* __restrict__ y) {
  __shared__ unsigned short Gs[64 * 72];
  __shared__ unsigned short Zs[64 * 72];      // z^T [d][s]
  __shared__ unsigned short P2s[4][32 * 72];  // per wave [tok][s]
  int tc = blockIdx.x, bh = blockIdx.y, b = bh >> 3, h = bh & 7;
  int tid = threadIdx.x, w = tid >> 6, lane = tid & 63, l = lane & 15, g = lane >> 4;
  {
    int s = tid >> 2, dc = (tid & 3) * 16;
    const float* src = qg + ((size_t)h * 64 + s) * 64 + dc;
    u16x8 o0, o1;
#pragma unroll
    for (int e = 0; e < 8; ++e) { o0[e] = f2bf(src[e]); o1[e] = f2bf(src[8 + e]); }
    *(u16x8*)&Gs[s * 72 + dc] = o0;
    *(u16x8*)&Gs[s * 72 + dc + 8] = o1;
#pragma unroll
    for (int j = 0; j < 2; ++j) {
      int cc = j * 256 + tid;
      int d2 = cc >> 3, sc8 = (cc & 7) * 8;
      *(u16x8*)&Zs[d2 * 72 + sc8] = *(const u16x8*)&zT[((size_t)bh * 64 + d2) * 64 + sc8];
    }
  }
  __syncthreads();
  for (int it = 0; it < 4; ++it) {
    int tok0 = tc * 512 + w * 128 + it * 32;
    bf16x8 ak[2][2];
#pragma unroll
    for (int fm = 0; fm < 2; ++fm)
#pragma unroll
      for (int ks = 0; ks < 2; ++ks)
        ak[fm][ks] = *(const bf16x8*)&kv[((size_t)(b * 16384) + tok0 + fm * 16 + l) * 1024 +
                                         h * 64 + ks * 32 + g * 8];
    f32x4 sacc[2][4] = {};
#pragma unroll
    for (int ks = 0; ks < 2; ++ks)
#pragma unroll
      for (int fs = 0; fs < 4; ++fs) {
        bf16x8 bq = *(const bf16x8*)&Gs[(fs * 16 + l) * 72 + ks * 32 + g * 8];
#pragma unroll
        for (int fm = 0; fm < 2; ++fm) sacc[fm][fs] = mfma16(ak[fm][ks], bq, sacc[fm][fs]);
      }
    float inv_[2][4];
#pragma unroll
    for (int fm = 0; fm < 2; ++fm) {
      float mx[4];
#pragma unroll
      for (int r = 0; r < 4; ++r) {
        float m4 = fmaxf(fmaxf(sacc[fm][0][r], sacc[fm][1][r]),
                         fmaxf(sacc[fm][2][r], sacc[fm][3][r]));
#pragma unroll
        for (int msk = 1; msk < 16; msk <<= 1) m4 = fmaxf(m4, __shfl_xor(m4, msk));
        mx[r] = m4;
      }
#pragma unroll
      for (int r = 0; r < 4; ++r) {
        float s4 = 0.f;
#pragma unroll
        for (int fs = 0; fs < 4; ++fs) {
          float p = __expf(sacc[fm][fs][r] - mx[r]);
          sacc[fm][fs][r] = p;
          s4 += p;
        }
#pragma unroll
        for (int msk = 1; msk < 16; msk <<= 1) s4 += __shfl_xor(s4, msk);
        inv_[fm][r] = 1.f / s4;
      }
#pragma unroll
      for (int fs = 0; fs < 4; ++fs)
#pragma unroll
        for (int r = 0; r < 4; ++r)
          P2s[w][(fm * 16 + g * 4 + r) * 72 + fs * 16 + l] = f2bf(sacc[fm][fs][r]);
    }
    f32x4 yacc[2][4] = {};
#pragma unroll
    for (int kc = 0; kc < 2; ++kc) {
      bf16x8 aP[2];
#pragma unroll
      for (int fm = 0; fm < 2; ++fm)
        aP[fm] = *(const bf16x8*)&P2s[w][(fm * 16 + l) * 72 + kc * 32 + g * 8];
#pragma unroll
      for (int fd = 0; fd < 4; ++fd) {
        bf16x8 bz = *(const bf16x8*)&Zs[(fd * 16 + l) * 72 + kc * 32 + g * 8];
#pragma unroll
        for (int fm = 0; fm < 2; ++fm) yacc[fm][fd] = mfma16(aP[fm], bz, yacc[fm][fd]);
      }
    }
#pragma unroll
    for (int fm = 0; fm < 2; ++fm)
#pragma unroll
      for (int fd = 0; fd < 4; ++fd)
#pragma unroll
        for (int r = 0; r < 4; ++r) {
          int tok = tok0 + fm * 16 + g * 4 + r;
          y[((size_t)(b * 16384) + tok) * 512 + h * 64 + fd * 16 + l] =
              f2bf(yacc[fm][fd][r] * inv_[fm][r]);
        }
  }
}

extern "C" void kernel_launch(void* const* d_in, const int* in_sizes, int n_in,
                              void* d_out, int out_size, void* d_ws, size_t ws_size,
                              hipStream_t stream) {
  const float* x  = (const float*)d_in[0];
  const float* qg = (const float*)d_in[1];
  const float* Wx = (const float*)d_in[2];
  const float* bx = (const float*)d_in[3];
  const float* Wk = (const float*)d_in[4];
  const float* bk = (const float*)d_in[5];
  const float* Wv = (const float*)d_in[6];
  const float* bv = (const float*)d_in[7];
  const float* Wo = (const float*)d_in[8];
  const float* bo = (const float*)d_in[9];
  float* out = (float*)d_out;

  char* ws = (char*)d_ws;
  unsigned short* xbf  = (unsigned short*)(ws);               // 64 MiB (later reused as y)
  unsigned short* vT   = (unsigned short*)(ws + 67108864);    // 64 MiB
  unsigned short* WkvT = (unsigned short*)(ws + 134217728);   // 1 MiB
  unsigned short* WoT  = (unsigned short*)(ws + 135266304);   // 0.5 MiB
  float* bkv           = (float*)(ws + 135790592);            // 4 KiB
  float* zpart         = (float*)(ws + 135794688);            // 8 MiB
  float* mpart         = (float*)(ws + 144183296);            // 128 KiB
  float* dpart         = (float*)(ws + 144314368);            // 128 KiB
  unsigned short* zT   = (unsigned short*)(ws + 144445440);   // 256 KiB
  unsigned short* kvbuf = (unsigned short*)d_out;             // 128 MiB, exact fit; dead before final GEMM

  k_cvt_bf16<<<dim3(16384), dim3(256), 0, stream>>>(x, xbf, 4194304);
  k_fuse_wkv<<<dim3(2048), dim3(256), 0, stream>>>(Wx, Wk, Wv, WkvT);
  k_fuse_bias<<<dim3(4), dim3(256), 0, stream>>>(bx, bk, bv, Wk, Wv, bkv);
  k_wo_t<<<dim3(1024), dim3(256), 0, stream>>>(Wo, WoT);
  // kv = x @ Wkv_fused + b  -> [65536, 1024] bf16 (k cols 0..511, v cols 512..1023)
  k_gemm<1><<<dim3(512, 8), dim3(256), 0, stream>>>(xbf, 512, WkvT, bkv, (void*)kvbuf, 1024);
  k_vT<<<dim3(256, 32), dim3(256), 0, stream>>>(kvbuf, vT);
  k_pass1<<<dim3(16, 32), dim3(256), 0, stream>>>(kvbuf, vT, qg, zpart, mpart, dpart);
  k_zred<<<dim3(32), dim3(256), 0, stream>>>(zpart, mpart, dpart, zT);
  k_pass2<<<dim3(32, 32), dim3(256), 0, stream>>>(kvbuf, zT, qg, xbf);
  // out = y @ Wo + bo  (reads xbf (=y), writes d_out over dead kv buffer)
  k_gemm<0><<<dim3(512, 4), dim3(256), 0, stream>>>(xbf, 512, WoT, bo, (void*)out, 512);
}

// Round 2
// 327.255 us; speedup vs baseline: 1.1417x; 1.1417x over previous
//
#include <hip/hip_runtime.h>
#include <stdint.h>

#define DEV __device__ __forceinline__

typedef __attribute__((ext_vector_type(8))) short bf16x8;
typedef __attribute__((ext_vector_type(4))) float f32x4;
typedef __attribute__((ext_vector_type(8))) unsigned short u16x8;
typedef __attribute__((ext_vector_type(4))) unsigned short u16x4;

DEV unsigned short f2bf(float f) {
  union { float f; unsigned int u; } v; v.f = f;
  unsigned int u = v.u;
  return (unsigned short)((u + 0x7FFFu + ((u >> 16) & 1u)) >> 16);
}

DEV f32x4 mfma16(bf16x8 a, bf16x8 b, f32x4 c) {
  return __builtin_amdgcn_mfma_f32_16x16x32_bf16(a, b, c, 0, 0, 0);
}

DEV void gl_lds16(const void* g, void* l) {
  __builtin_amdgcn_global_load_lds(
      (const __attribute__((address_space(1))) void*)g,
      (__attribute__((address_space(3))) void*)l, 16, 0, 0);
}

// ---------------- convert x (fp32 -> bf16), vectorized ----------------
__global__ __launch_bounds__(256) void k_cvt_bf16(const float* __restrict__ in,
                                                  unsigned short* __restrict__ out,
                                                  int n8) {
  int i = blockIdx.x * 256 + threadIdx.x;
  if (i >= n8) return;
  const float4* p = (const float4*)in + (size_t)i * 2;
  float4 a = p[0], b = p[1];
  u16x8 o;
  o[0] = f2bf(a.x); o[1] = f2bf(a.y); o[2] = f2bf(a.z); o[3] = f2bf(a.w);
  o[4] = f2bf(b.x); o[5] = f2bf(b.y); o[6] = f2bf(b.z); o[7] = f2bf(b.w);
  ((u16x8*)out)[i] = o;
}

// -------- fused weights: WkvT[o][c] = sum_d Wx[c][hb+d] * W{k,v}[d][dp] --------
__global__ __launch_bounds__(256) void k_fuse_wkv(const float* __restrict__ Wx,
                                                  const float* __restrict__ Wk,
                                                  const float* __restrict__ Wv,
                                                  unsigned short* __restrict__ WkvT) {
  int idx = blockIdx.x * 256 + threadIdx.x;  // 524288
  int o = idx >> 9;                          // 0..1023
  int c = idx & 511;
  const float* W = (o < 512) ? Wk : Wv;
  int oo = o & 511;
  int hb = oo & ~63;  // h*64
  int dp = oo & 63;
  float s = 0.f;
#pragma unroll 8
  for (int d = 0; d < 64; ++d) s += Wx[(size_t)c * 512 + hb + d] * W[d * 64 + dp];
  WkvT[(size_t)o * 512 + c] = f2bf(s);
}

__global__ void k_fuse_bias(const float* __restrict__ bx, const float* __restrict__ bk,
                            const float* __restrict__ bv, const float* __restrict__ Wk,
                            const float* __restrict__ Wv, float* __restrict__ bkv) {
  int o = blockIdx.x * 256 + threadIdx.x;  // 1024
  if (o >= 1024) return;
  const float* W = (o < 512) ? Wk : Wv;
  const float* bb = (o < 512) ? bk : bv;
  int oo = o & 511, hb = oo & ~63, dp = oo & 63;
  float s = bb[dp];
  for (int d = 0; d < 64; ++d) s += bx[hb + d] * W[d * 64 + dp];
  bkv[o] = s;
}

__global__ void k_wo_t(const float* __restrict__ Wo, unsigned short* __restrict__ WoT) {
  int idx = blockIdx.x * 256 + threadIdx.x;  // 262144
  int i = idx >> 9, o = idx & 511;
  WoT[(size_t)o * 512 + i] = f2bf(Wo[(size_t)i * 512 + o]);
}

// ---------------- GEMM: C[M,Nw] = A[M,512] @ BT[Nw,512]^T + bias ----------------
// 128x128 tile, BK=64, 4 waves (2x2), global_load_lds width 16,
// 2-phase prefetch double-buffer (T3 minimum), XCD-chunked 1-D grid (N-tile fastest).
// MODE 0: C fp32 [M][512].  MODE 1: kv split -> k bf16 [M][512], v -> vT[bh][d][n].
template <int MODE>
__global__ __launch_bounds__(256) void k_gemm(const unsigned short* __restrict__ A,
                                              const unsigned short* __restrict__ BT,
                                              const float* __restrict__ bias,
                                              void* __restrict__ Cptr,
                                              unsigned short* __restrict__ vT, int NT) {
  __shared__ unsigned short As[2][128 * 64];
  __shared__ unsigned short Bs[2][128 * 64];
  const int tid = threadIdx.x;
  const int w = tid >> 6, lane = tid & 63;
  const int l = lane & 15, g = lane >> 4;
  // XCD-chunked swizzle: each XCD gets a contiguous run of (mtile, all ntiles)
  unsigned bid = blockIdx.x;
  unsigned perx = gridDim.x >> 3;
  unsigned nbid = (bid & 7) * perx + (bid >> 3);
  const int ntile = nbid % NT, mtile = nbid / NT;
  const int bm = mtile * 128, bn = ntile * 128;
  const int wm = (w >> 1) * 64, wn = (w & 1) * 64;
  const int lr = lane >> 3;        // row within 8-row chunk
  const int lc = (lane & 7) * 8;   // k elem offset (16B)
  f32x4 acc[4][4] = {};

#define STAGE(buf, k0)                                                        \
  {                                                                           \
    _Pragma("unroll") for (int i = 0; i < 4; ++i) {                           \
      int q = w * 4 + i;                                                      \
      int row = q * 8 + lr;                                                   \
      gl_lds16(A + (size_t)(bm + row) * 512 + (k0) + lc, &As[buf][q * 512]);  \
      gl_lds16(BT + (size_t)(bn + row) * 512 + (k0) + lc, &Bs[buf][q * 512]); \
    }                                                                         \
  }

  STAGE(0, 0);
  __syncthreads();  // drains vmcnt(0): buffer 0 staged
  int cur = 0;
#pragma unroll 2
  for (int t = 0; t < 8; ++t) {
    if (t < 7) STAGE(cur ^ 1, (t + 1) * 64);  // prefetch next tile (overlaps MFMA below)
#pragma unroll
    for (int ks = 0; ks < 2; ++ks) {
      bf16x8 af[4], bfr[4];
#pragma unroll
      for (int fm = 0; fm < 4; ++fm)
        af[fm] = *(const bf16x8*)&As[cur][(wm + fm * 16 + l) * 64 + ks * 32 + g * 8];
#pragma unroll
      for (int fn = 0; fn < 4; ++fn)
        bfr[fn] = *(const bf16x8*)&Bs[cur][(wn + fn * 16 + l) * 64 + ks * 32 + g * 8];
#pragma unroll
      for (int fm = 0; fm < 4; ++fm)
#pragma unroll
        for (int fn = 0; fn < 4; ++fn)
          acc[fm][fn] = mfma16(af[fm], bfr[fn], acc[fm][fn]);
    }
    __syncthreads();  // drains vmcnt(0): next buffer staged; cur reads done in all waves
    cur ^= 1;
  }
#undef STAGE

#pragma unroll
  for (int fm = 0; fm < 4; ++fm)
#pragma unroll
    for (int fn = 0; fn < 4; ++fn) {
      int colg = bn + wn + fn * 16 + l;  // global output column
      float bcol = bias[colg];
      int row0 = bm + wm + fm * 16 + g * 4;
      if (MODE == 0) {
#pragma unroll
        for (int r = 0; r < 4; ++r)
          ((float*)Cptr)[(size_t)(row0 + r) * 512 + colg] = acc[fm][fn][r] + bcol;
      } else {
        if (colg < 512) {  // k half (wave-uniform branch: 512 is a multiple of 16)
#pragma unroll
          for (int r = 0; r < 4; ++r)
            ((unsigned short*)Cptr)[(size_t)(row0 + r) * 512 + colg] =
                f2bf(acc[fm][fn][r] + bcol);
        } else {  // v half -> transposed vT[(b*8+h)*64+d][n]
          int c2 = colg - 512, h = c2 >> 6, d = c2 & 63;
          int b = row0 >> 14, nn = row0 & 16383;
          u16x4 o;
#pragma unroll
          for (int r = 0; r < 4; ++r) o[r] = f2bf(acc[fm][fn][r] + bcol);
          *(u16x4*)&vT[(((size_t)(b * 8 + h)) * 64 + d) * 16384 + nn] = o;
        }
      }
    }
}

// ---------------- pass 1: flash attn, 64 queries x 16384 keys, key-split ----------------
__global__ __launch_bounds__(256) void k_pass1(const unsigned short* __restrict__ kb,
                                               const unsigned short* __restrict__ vT,
                                               const float* __restrict__ qg,
                                               float* __restrict__ zpart,
                                               float* __restrict__ mpart,
                                               float* __restrict__ dpart) {
  __shared__ unsigned short Gs[64 * 72];   // [s][d] pad
  __shared__ unsigned short Ks[128 * 72];  // [n][d] pad
  __shared__ unsigned short Vs[64 * 136];  // [d][n] pad
  __shared__ unsigned short Ps[64 * 136];  // [s][n] pad
  int chunk = blockIdx.x, bh = blockIdx.y;
  int b = bh >> 3, h = bh & 7;
  int tid = threadIdx.x, w = tid >> 6, lane = tid & 63, l = lane & 15, g = lane >> 4;
  {
    int s = tid >> 2, dc = (tid & 3) * 16;
    const float* src = qg + ((size_t)h * 64 + s) * 64 + dc;
    u16x8 o0, o1;
#pragma unroll
    for (int e = 0; e < 8; ++e) { o0[e] = f2bf(src[e]); o1[e] = f2bf(src[8 + e]); }
    *(u16x8*)&Gs[s * 72 + dc] = o0;
    *(u16x8*)&Gs[s * 72 + dc + 8] = o1;
  }
  f32x4 zacc[4] = {};
  float m_run = -1e30f, d_run = 0.f;
  int n_base = chunk * 1024;
  for (int t = 0; t < 8; ++t) {
    int n0 = n_base + t * 128;
#pragma unroll
    for (int i = 0; i < 4; ++i) {  // stage K tile [128][64]
      int cc = i * 256 + tid;
      int nl = cc >> 3, dc = (cc & 7) * 8;
      *(u16x8*)&Ks[nl * 72 + dc] =
          *(const u16x8*)&kb[((size_t)(b * 16384 + n0 + nl)) * 512 + h * 64 + dc];
    }
#pragma unroll
    for (int i = 0; i < 4; ++i) {  // stage V^T tile [64][128]
      int cc = i * 256 + tid;
      int d = cc >> 4, nc = (cc & 15) * 8;
      *(u16x8*)&Vs[d * 136 + nc] =
          *(const u16x8*)&vT[((size_t)(bh * 64 + d)) * 16384 + n0 + nc];
    }
    __syncthreads();
    // logits^T = K_tile @ G^T : [128 keys, 16 queries per wave]
    f32x4 sacc[8] = {};
#pragma unroll
    for (int ks = 0; ks < 2; ++ks) {
      bf16x8 bq = *(const bf16x8*)&Gs[(w * 16 + l) * 72 + ks * 32 + g * 8];
#pragma unroll
      for (int fm = 0; fm < 8; ++fm) {
        bf16x8 ak = *(const bf16x8*)&Ks[(fm * 16 + l) * 72 + ks * 32 + g * 8];
        sacc[fm] = mfma16(ak, bq, sacc[fm]);
      }
    }
    // online softmax over keys (rows): reduce across g-groups (lanes ^16, ^32)
    float tmax = -1e30f;
#pragma unroll
    for (int fm = 0; fm < 8; ++fm)
#pragma unroll
      for (int r = 0; r < 4; ++r) tmax = fmaxf(tmax, sacc[fm][r]);
    tmax = fmaxf(tmax, __shfl_xor(tmax, 16));
    tmax = fmaxf(tmax, __shfl_xor(tmax, 32));
    float newm = fmaxf(m_run, tmax);
    float scale = __expf(m_run - newm);
    float psum = 0.f;
#pragma unroll
    for (int fm = 0; fm < 8; ++fm) {
      u16x4 pp;
#pragma unroll
      for (int r = 0; r < 4; ++r) {
        float p = __expf(sacc[fm][r] - newm);
        psum += p;
        pp[r] = f2bf(p);
      }
      *(u16x4*)&Ps[(w * 16 + l) * 136 + fm * 16 + g * 4] = pp;
    }
    psum += __shfl_xor(psum, 16);
    psum += __shfl_xor(psum, 32);
    d_run = d_run * scale + psum;
    m_run = newm;
    float sc[4];
#pragma unroll
    for (int r = 0; r < 4; ++r) sc[r] = __shfl(scale, g * 4 + r);
#pragma unroll
    for (int fd = 0; fd < 4; ++fd)
#pragma unroll
      for (int r = 0; r < 4; ++r) zacc[fd][r] *= sc[r];
    // z += P @ v  (A = P rows from Ps, B = v via Vs[d][n])
#pragma unroll
    for (int kc = 0; kc < 4; ++kc) {
      bf16x8 ap = *(const bf16x8*)&Ps[(w * 16 + l) * 136 + kc * 32 + g * 8];
#pragma unroll
      for (int fd = 0; fd < 4; ++fd) {
        bf16x8 bv = *(const bf16x8*)&Vs[(fd * 16 + l) * 136 + kc * 32 + g * 8];
        zacc[fd] = mfma16(ap, bv, zacc[fd]);
      }
    }
    __syncthreads();
  }
  size_t base = ((size_t)bh * 16 + chunk) * 64;
#pragma unroll
  for (int fd = 0; fd < 4; ++fd)
#pragma unroll
    for (int r = 0; r < 4; ++r) {
      int s = w * 16 + g * 4 + r, d = fd * 16 + l;
      zpart[(base + s) * 64 + d] = zacc[fd][r];
    }
  if (g == 0) {
    mpart[base + w * 16 + l] = m_run;
    dpart[base + w * 16 + l] = d_run;
  }
}

// ---------------- reduce partials -> zT bf16 [bh][d][s] ----------------
__global__ void k_zred(const float* __restrict__ zpart, const float* __restrict__ mpart,
                       const float* __restrict__ dpart, unsigned short* __restrict__ zT) {
  int bh = blockIdx.x, tid = threadIdx.x;
  for (int i = 0; i < 16; ++i) {
    int idx = i * 256 + tid;  // 0..4095
    int s = idx >> 6, d = idx & 63;
    float mg = -1e30f;
    for (int c = 0; c < 16; ++c) mg = fmaxf(mg, mpart[((size_t)bh * 16 + c) * 64 + s]);
    float den = 0.f, num = 0.f;
    for (int c = 0; c < 16; ++c) {
      float e = __expf(mpart[((size_t)bh * 16 + c) * 64 + s] - mg);
      den += e * dpart[((size_t)bh * 16 + c) * 64 + s];
      num += e * zpart[(((size_t)bh * 16 + c) * 64 + s) * 64 + d];
    }
    zT[((size_t)bh * 64 + d) * 64 + s] = f2bf(num / den);
  }
}

// ---------------- pass 2: per-token softmax over 64 slots, y = P2 @ z ----------------
__global__ __launch_bounds__(256) void k_pass2(const unsigned short* __restrict__ kb,
                                               const unsigned short* __restrict__ zT,
                                               const float* __restrict__ qg,
                                               unsigned short* __restrict__ y) {
  __shared__ unsigned short Gs[64 * 72];
  __shared__ unsigned short Zs[64 * 72];      // z^T [d][s]
  __shared__ unsigned short P2s[4][32 * 72];  // per wave [tok][s]
  int tc = blockIdx.x, bh = blockIdx.y, b = bh >> 3, h = bh & 7;
  int tid = threadIdx.x, w = tid >> 6, lane = tid & 63, l = lane & 15, g = lane >> 4;
  {
    int s = tid >> 2, dc = (tid & 3) * 16;
    const float* src = qg + ((size_t)h * 64 + s) * 64 + dc;
    u16x8 o0, o1;
#pragma unroll
    for (int e = 0; e < 8; ++e) { o0[e] = f2bf(src[e]); o1[e] = f2bf(src[8 + e]); }
    *(u16x8*)&Gs[s * 72 + dc] = o0;
    *(u16x8*)&Gs[s * 72 + dc + 8] = o1;
#pragma unroll
    for (int j = 0; j < 2; ++j) {
      int cc = j * 256 + tid;
      int d2 = cc >> 3, sc8 = (cc & 7) * 8;
      *(u16x8*)&Zs[d2 * 72 + sc8] = *(const u16x8*)&zT[((size_t)bh * 64 + d2) * 64 + sc8];
    }
  }
  __syncthreads();
  for (int it = 0; it < 4; ++it) {
    int tok0 = tc * 512 + w * 128 + it * 32;
    bf16x8 ak[2][2];
#pragma unroll
    for (int fm = 0; fm < 2; ++fm)
#pragma unroll
      for (int ks = 0; ks < 2; ++ks)
        ak[fm][ks] = *(const bf16x8*)&kb[((size_t)(b * 16384) + tok0 + fm * 16 + l) * 512 +
                                         h * 64 + ks * 32 + g * 8];
    f32x4 sacc[2][4] = {};
#pragma unroll
    for (int ks = 0; ks < 2; ++ks)
#pragma unroll
      for (int fs = 0; fs < 4; ++fs) {
        bf16x8 bq = *(const bf16x8*)&Gs[(fs * 16 + l) * 72 + ks * 32 + g * 8];
#pragma unroll
        for (int fm = 0; fm < 2; ++fm) sacc[fm][fs] = mfma16(ak[fm][ks], bq, sacc[fm][fs]);
      }
    float inv_[2][4];
#pragma unroll
    for (int fm = 0; fm < 2; ++fm) {
      float mx[4];
#pragma unroll
      for (int r = 0; r < 4; ++r) {
        float m4 = fmaxf(fmaxf(sacc[fm][0][r], sacc[fm][1][r]),
                         fmaxf(sacc[fm][2][r], sacc[fm][3][r]));
#pragma unroll
        for (int msk = 1; msk < 16; msk <<= 1) m4 = fmaxf(m4, __shfl_xor(m4, msk));
        mx[r] = m4;
      }
#pragma unroll
      for (int r = 0; r < 4; ++r) {
        float s4 = 0.f;
#pragma unroll
        for (int fs = 0; fs < 4; ++fs) {
          float p = __expf(sacc[fm][fs][r] - mx[r]);
          sacc[fm][fs][r] = p;
          s4 += p;
        }
#pragma unroll
        for (int msk = 1; msk < 16; msk <<= 1) s4 += __shfl_xor(s4, msk);
        inv_[fm][r] = 1.f / s4;
      }
#pragma unroll
      for (int fs = 0; fs < 4; ++fs)
#pragma unroll
        for (int r = 0; r < 4; ++r)
          P2s[w][(fm * 16 + g * 4 + r) * 72 + fs * 16 + l] = f2bf(sacc[fm][fs][r]);
    }
    f32x4 yacc[2][4] = {};
#pragma unroll
    for (int kc = 0; kc < 2; ++kc) {
      bf16x8 aP[2];
#pragma unroll
      for (int fm = 0; fm < 2; ++fm)
        aP[fm] = *(const bf16x8*)&P2s[w][(fm * 16 + l) * 72 + kc * 32 + g * 8];
#pragma unroll
      for (int fd = 0; fd < 4; ++fd) {
        bf16x8 bz = *(const bf16x8*)&Zs[(fd * 16 + l) * 72 + kc * 32 + g * 8];
#pragma unroll
        for (int fm = 0; fm < 2; ++fm) yacc[fm][fd] = mfma16(aP[fm], bz, yacc[fm][fd]);
      }
    }
#pragma unroll
    for (int fm = 0; fm < 2; ++fm)
#pragma unroll
      for (int fd = 0; fd < 4; ++fd)
#pragma unroll
        for (int r = 0; r < 4; ++r) {
          int tok = tok0 + fm * 16 + g * 4 + r;
          y[((size_t)(b * 16384) + tok) * 512 + h * 64 + fd * 16 + l] =
              f2bf(yacc[fm][fd][r] * inv_[fm][r]);
        }
  }
}

extern "C" void kernel_launch(void* const* d_in, const int* in_sizes, int n_in,
                              void* d_out, int out_size, void* d_ws, size_t ws_size,
                              hipStream_t stream) {
  const float* x  = (const float*)d_in[0];
  const float* qg = (const float*)d_in[1];
  const float* Wx = (const float*)d_in[2];
  const float* bx = (const float*)d_in[3];
  const float* Wk = (const float*)d_in[4];
  const float* bk = (const float*)d_in[5];
  const float* Wv = (const float*)d_in[6];
  const float* bv = (const float*)d_in[7];
  const float* Wo = (const float*)d_in[8];
  const float* bo = (const float*)d_in[9];
  float* out = (float*)d_out;

  char* ws = (char*)d_ws;
  unsigned short* xbf  = (unsigned short*)(ws);               // 64 MiB (reused as y after kv-GEMM)
  unsigned short* vT   = (unsigned short*)(ws + 67108864);    // 64 MiB
  unsigned short* WkvT = (unsigned short*)(ws + 134217728);   // 1 MiB
  unsigned short* WoT  = (unsigned short*)(ws + 135266304);   // 0.5 MiB
  float* bkv           = (float*)(ws + 135790592);            // 4 KiB
  float* zpart         = (float*)(ws + 135794688);            // 8 MiB
  float* mpart         = (float*)(ws + 144183296);            // 128 KiB
  float* dpart         = (float*)(ws + 144314368);            // 128 KiB
  unsigned short* zT   = (unsigned short*)(ws + 144445440);   // 256 KiB
  unsigned short* kbuf = (unsigned short*)d_out;              // 64 MiB in d_out; dead before final GEMM

  k_cvt_bf16<<<dim3(16384), dim3(256), 0, stream>>>(x, xbf, 4194304);
  k_fuse_wkv<<<dim3(2048), dim3(256), 0, stream>>>(Wx, Wk, Wv, WkvT);
  k_fuse_bias<<<dim3(4), dim3(256), 0, stream>>>(bx, bk, bv, Wk, Wv, bkv);
  k_wo_t<<<dim3(1024), dim3(256), 0, stream>>>(Wo, WoT);
  // kv = x @ Wkv_fused + b: k half -> kbuf [65536][512] bf16, v half -> vT [32][64][16384]
  k_gemm<1><<<dim3(4096), dim3(256), 0, stream>>>(xbf, WkvT, bkv, (void*)kbuf, vT, 8);
  k_pass1<<<dim3(16, 32), dim3(256), 0, stream>>>(kbuf, vT, qg, zpart, mpart, dpart);
  k_zred<<<dim3(32), dim3(256), 0, stream>>>(zpart, mpart, dpart, zT);
  k_pass2<<<dim3(32, 32), dim3(256), 0, stream>>>(kbuf, zT, qg, xbf);
  // out = y @ Wo + bo (reads xbf (=y), writes full d_out over dead kbuf)
  k_gemm<0><<<dim3(2048), dim3(256), 0, stream>>>(xbf, WoT, bo, (void*)out, nullptr, 4);
}